// Round 3
// baseline (567.213 us; speedup 1.0000x reference)
//
#include <hip/hip_runtime.h>
#include <hip/hip_bf16.h>

#define D_IN  500
#define BATCH 131072
#define BM    64

typedef unsigned short u16;
typedef unsigned int   u32;
using f32x4  = __attribute__((ext_vector_type(4))) float;
using bf16x8 = __attribute__((ext_vector_type(8))) short;

__device__ __forceinline__ u16 f2bf(float f) {
  u32 b = __builtin_bit_cast(u32, f);
  b += 0x7FFFu + ((b >> 16) & 1u);
  return (u16)(b >> 16);
}
__device__ __forceinline__ float bf2f(u32 hbits) {
  return __builtin_bit_cast(float, hbits << 16);
}

// XLA/Eigen fast-tanh f32 (clamped rational) — matches jnp.tanh on XLA backends.
__device__ __forceinline__ float xla_tanh(float z) {
  float xc = fminf(fmaxf(z, -7.90531110764903f), 7.90531110764903f);
  float x2 = xc * xc;
  float p = fmaf(x2, -2.76076847742355e-16f, 2.00018790482477e-13f);
  p = fmaf(x2, p, -8.60467152213735e-11f);
  p = fmaf(x2, p,  5.12229709037114e-08f);
  p = fmaf(x2, p,  1.48572235717979e-05f);
  p = fmaf(x2, p,  6.37261928875436e-04f);
  p = fmaf(x2, p,  4.89352455891786e-03f);
  p = xc * p;
  float q = fmaf(x2, 1.19825839466702e-06f, 1.18534705686654e-04f);
  q = fmaf(x2, q, 2.26843463243900e-03f);
  q = fmaf(x2, q, 4.89352518554385e-03f);
  return (fabsf(z) < 0.0004f) ? z : (p / q);
}

// ---------------------------------------------------------------------------
// prep: build extended bf16 B-matrix (Omega^T | one-hots | beta | alpha | ones)
// in MFMA A-fragment order (544 frag-blocks of 1 KB), plus:
//   thr[512]  : nnz thresholds  t_c = 0.001 - x_bw[c]  (pad cols -> +inf)
//   smalls[0] : sum(x_bw)   smalls[1] : l_all accumulator (zeroed)
// Main blocks (blk<512): id = chunk*32 + nw*16 + jg*4 + ks
//   n = chunk*32 + nw*16 + (lane&15);  j = jg*128 + ks*32 + (lane>>4)*8 + e
// Extras (blk>=512): id = 512 + (nw*4+jg)*4 + ks ; n = 512 + nw*16 + (lane&15)
// ---------------------------------------------------------------------------
__global__ void disc_prep(const float* __restrict__ Omega,
                          const float* __restrict__ alpha,
                          const float* __restrict__ beta,
                          const float* __restrict__ x_bw,
                          const int* __restrict__ sector_id,
                          const int* __restrict__ mq_id,
                          u16* __restrict__ wsA,
                          float* __restrict__ thr,
                          float* __restrict__ smalls) {
  int idx = blockIdx.x * 256 + threadIdx.x;   // over 544*512 = 278528 elements
  if (idx == 1) smalls[1] = 0.0f;             // l_all
  if (idx < 512) thr[idx] = (idx < D_IN) ? (0.001f - x_bw[idx]) : 3.0e38f;
  if (blockIdx.x == 0 && threadIdx.x < 64) {  // sum(x_bw) by wave 0
    float s = 0.f;
    for (int c = threadIdx.x; c < D_IN; c += 64) s += x_bw[c];
    #pragma unroll
    for (int m = 1; m < 64; m <<= 1) s += __shfl_xor(s, m, 64);
    if (threadIdx.x == 0) smalls[0] = s;
  }
  if (idx >= 544 * 512) return;
  int blk    = idx >> 9;
  int within = idx & 511;
  int lane   = within >> 3;
  int e      = within & 7;
  int n, j;
  if (blk < 512) {
    int chunk = blk >> 5;
    int nw    = (blk >> 4) & 1;
    int jg    = (blk >> 2) & 3;
    int ks    = blk & 3;
    n = chunk * 32 + nw * 16 + (lane & 15);
    j = jg * 128 + ks * 32 + ((lane >> 4) << 3) + e;
  } else {
    int b4  = blk - 512;
    int sub = b4 >> 2;
    int ks  = b4 & 3;
    int nw = sub >> 2, jg = sub & 3;
    n = 512 + nw * 16 + (lane & 15);
    j = jg * 128 + ks * 32 + ((lane >> 4) << 3) + e;
  }
  float v = 0.0f;
  if (j < D_IN) {
    if (n < D_IN)       v = Omega[j * D_IN + n];
    else if (n < 512)   v = 0.0f;                                  // N pad
    else if (n < 523)   v = (sector_id[j] == (n - 512)) ? 1.0f : 0.0f;
    else if (n < 533)   v = (mq_id[j]     == (n - 523)) ? 1.0f : 0.0f;
    else if (n == 533)  v = beta[j];
    else if (n == 534)  v = alpha[j];
    else if (n == 535)  v = 1.0f;                                  // ones -> sum(d)
  }
  wsA[idx] = f2bf(v);
}

// ---------------------------------------------------------------------------
// main: per 64-row block:
//  staging: unrolled x16 coalesced float4 load -> bf16 d in swizzled LDS
//  stats:   sabs / nnz computed from the bf16 bfs fragments (no x re-read)
//  GEMM:    C'[n,i] = sum_j W[j,n] * d[i,j] via mfma_f32_16x16x32_bf16.
//           8 waves = 2 nw x 4 jg; bfs (wave's d^T K-slice) register-resident;
//           16 chunks with zero-reg af prefetch (chunk 15 prefetches extras).
// ---------------------------------------------------------------------------
__global__ __launch_bounds__(512, 2) void disc_main(
    const float* __restrict__ x, const float* __restrict__ x_bw,
    const u16* __restrict__ wsA, const float* __restrict__ thr,
    const float* __restrict__ smalls,
    float* __restrict__ tot_out, float* __restrict__ l_all) {
  __shared__ alignas(16) u16 ldsA[BM * 512];  // 64 KB, swizzled: byte ^= (row&7)<<4
  __shared__ float s_ext[BM][25];             // stride 25: conflict-free atomics
  __shared__ float s_dqd[BM][8];
  __shared__ float s_sabs[BM];
  __shared__ float s_nnz[BM];

  const int t = threadIdx.x;
  const float* xblk = x + (size_t)blockIdx.x * (BM * D_IN);

  // zero extras/stat partials
  for (int z = t; z < BM * 25; z += 512) ((float*)s_ext)[z] = 0.0f;
  if (t < BM) { s_sabs[t] = 0.0f; s_nnz[t] = 0.0f; }

  // zero-pad d columns 500..511
  for (int z = t; z < BM * 12; z += 512) {
    int r = z / 12, c = 500 + (z - r * 12);
    int byte = ((r << 10) + (c << 1)) ^ ((r & 7) << 4);
    *(u16*)((char*)ldsA + byte) = 0;
  }

  // staging: unrolled, 16 independent dwordx4 loads in flight per thread
  #pragma unroll
  for (int k = 0; k < 16; ++k) {
    int v4 = t + k * 512;
    if (v4 < (BM * D_IN) / 4) {                 // 8000 float4s
      int r = (int)(((unsigned)v4 * 33555u) >> 22);   // v4 / 125, exact for v4<59073
      int c = v4 - r * 125;                      // float4 index within row
      float4 xv = *(const float4*)(xblk + r * D_IN + c * 4);
      float4 bw = *(const float4*)(x_bw + c * 4);
      u32 lo = (u32)f2bf(xv.x - bw.x) | ((u32)f2bf(xv.y - bw.y) << 16);
      u32 hi = (u32)f2bf(xv.z - bw.z) | ((u32)f2bf(xv.w - bw.w) << 16);
      int byte = ((r << 10) + (c << 3)) ^ ((r & 7) << 4);
      *(uint2*)((char*)ldsA + byte) = make_uint2(lo, hi);
    }
  }

  __syncthreads();

  // ---- GEMM phase (barrier-free) ----
  const int l   = t & 63;
  const int w   = t >> 6;
  const int nw  = w >> 2;     // n-half within 32-col chunk
  const int jg  = w & 3;      // K-slice (128 wide)
  const int l15 = l & 15;
  const int l4  = l >> 4;
  const f32x4 fzero = {0.f, 0.f, 0.f, 0.f};

  // preload the wave's entire d^T K-slice: bfs[ks][cf] covers
  // j in [jg*128+ks*32+l4*8, +8), i = cf*16+l15.   (64 VGPRs, pinned)
  bf16x8 bfs[4][4];
  #pragma unroll
  for (int ks = 0; ks < 4; ++ks) {
    const int kk = jg * 128 + ks * 32 + l4 * 8;
    #pragma unroll
    for (int cf = 0; cf < 4; ++cf) {
      int i = cf * 16 + l15;
      int byte = ((i << 10) + (kk << 1)) ^ ((i & 7) << 4);
      bfs[ks][cf] = *(const bf16x8*)((const char*)ldsA + byte);
    }
  }

  // stats from bfs: each (i,col) visited once (ks split across nw halves)
  {
    float psab[4] = {0.f, 0.f, 0.f, 0.f};
    float pnnz[4] = {0.f, 0.f, 0.f, 0.f};
    #pragma unroll
    for (int kq = 0; kq < 2; ++kq) {
      const int ks = nw * 2 + kq;
      const int kk = jg * 128 + ks * 32 + l4 * 8;
      float4 th0 = *(const float4*)(thr + kk);
      float4 th1 = *(const float4*)(thr + kk + 4);
      #pragma unroll
      for (int cf = 0; cf < 4; ++cf) {
        bf16x8 bv = bfs[ks][cf];
        #pragma unroll
        for (int e = 0; e < 8; ++e) {
          float dv = bf2f((u32)(u16)bv[e]);
          float th = (e < 4) ? ((const float*)&th0)[e] : ((const float*)&th1)[e - 4];
          psab[cf] += fabsf(dv);
          pnnz[cf] += (dv > th) ? 1.0f : 0.0f;
        }
      }
    }
    #pragma unroll
    for (int cf = 0; cf < 4; ++cf) {
      atomicAdd(&s_sabs[cf * 16 + l15], psab[cf]);
      atomicAdd(&s_nnz[cf * 16 + l15], pnnz[cf]);
    }
  }

  float pdqd[4] = {0.f, 0.f, 0.f, 0.f};
  const u16* wAl = wsA + (l << 3);
  const int fb0 = nw * 16 + jg * 4;

  bf16x8 af[4];
  #pragma unroll
  for (int ks = 0; ks < 4; ++ks)
    af[ks] = *(const bf16x8*)(wAl + ((fb0 + ks) << 9));

  #pragma unroll 1
  for (int chunk = 0; chunk < 16; ++chunk) {
    f32x4 acc[4] = {fzero, fzero, fzero, fzero};
    #pragma unroll
    for (int ks = 0; ks < 4; ++ks)
      #pragma unroll
      for (int cf = 0; cf < 4; ++cf)
        acc[cf] = __builtin_amdgcn_mfma_f32_16x16x32_bf16(af[ks], bfs[ks][cf], acc[cf], 0, 0, 0);
    // zero-reg prefetch: chunk+1's frags (chunk 15 -> extras frags)
    const int nb = (chunk < 15) ? ((chunk + 1) * 32 + fb0)
                                : (512 + (nw * 4 + jg) * 4);
    #pragma unroll
    for (int ks = 0; ks < 4; ++ks)
      af[ks] = *(const bf16x8*)(wAl + ((nb + ks) << 9));
    // dQd epilogue: C'[n,i] * d[i,n]; n = nbase..nbase+3 contiguous -> b64 read
    const int nbase = chunk * 32 + nw * 16 + l4 * 4;
    #pragma unroll
    for (int cf = 0; cf < 4; ++cf) {
      int i = cf * 16 + l15;
      int byte = ((i << 10) + (nbase << 1)) ^ ((i & 7) << 4);
      uint2 dv = *(const uint2*)((const char*)ldsA + byte);
      pdqd[cf] += acc[cf][0] * bf2f(dv.x & 0xFFFFu)
                + acc[cf][1] * bf2f(dv.x >> 16)
                + acc[cf][2] * bf2f(dv.y & 0xFFFFu)
                + acc[cf][3] * bf2f(dv.y >> 16);
    }
  }

  // extras (32 n-cols: sector, mq, beta, alpha, ones) — af already prefetched
  {
    f32x4 acc4[4];
    #pragma unroll
    for (int cf = 0; cf < 4; ++cf) acc4[cf] = fzero;
    #pragma unroll
    for (int ks = 0; ks < 4; ++ks)
      #pragma unroll
      for (int cf = 0; cf < 4; ++cf)
        acc4[cf] = __builtin_amdgcn_mfma_f32_16x16x32_bf16(af[ks], bfs[ks][cf], acc4[cf], 0, 0, 0);
    #pragma unroll
    for (int cf = 0; cf < 4; ++cf) {
      int i = cf * 16 + l15;
      #pragma unroll
      for (int q = 0; q < 4; ++q) {
        int n = 512 + nw * 16 + l4 * 4 + q;
        if (n < 536) atomicAdd(&s_ext[i][n - 512], acc4[cf][q]);
      }
    }
  }

  // reduce pdqd across the 4 lane-groups holding the same i
  #pragma unroll
  for (int cf = 0; cf < 4; ++cf) {
    float v = pdqd[cf];
    v += __shfl_xor(v, 16, 64);
    v += __shfl_xor(v, 32, 64);
    if (l < 16) s_dqd[cf * 16 + l][w] = v;
  }
  __syncthreads();

  // per-row assembly
  if (t < BM) {
    float dqd = 0.f;
    #pragma unroll
    for (int ww = 0; ww < 8; ++ww) dqd += s_dqd[t][ww];
    float tex = 0.f;
    #pragma unroll
    for (int c = 0; c < 22; ++c)                 // sector(11) + mq(10) + beta(1)
      tex += fmaxf(fabsf(s_ext[t][c]) - 0.1f, 0.f);
    float l2 = s_ext[t][22];                     // d @ alpha
    float sx = s_ext[t][23] + smalls[0];         // sum(d) + sum(x_bw) = sum(x)
    float sabs = s_sabs[t], nnz = s_nnz[t];
    float tot = tex
      + fmaxf(1.f - sx, 0.f) + fmaxf(sx - 1.f, 0.f)
      + fmaxf(sabs - 0.05f, 0.f)
      + fmaxf(nnz - 70.f, 0.f) + fmaxf(69.f - nnz, 0.f)
      + fmaxf(dqd - 0.01f, 0.f) + fmaxf(0.0025f - dqd, 0.f)
      + fmaxf(100.f * dqd - 100.f * l2 - 1000.f, 0.f);
    tot_out[(size_t)blockIdx.x * BM + t] = tot;
    float bs = sabs;
    #pragma unroll
    for (int m = 1; m < 64; m <<= 1) bs += __shfl_xor(bs, m, 64);
    if (t == 0) atomicAdd(l_all, bs);
  }
}

// ---------------------------------------------------------------------------
__global__ void disc_final(const float* __restrict__ tot_in,
                           const float* __restrict__ l_all,
                           float* __restrict__ out) {
  int i = blockIdx.x * 256 + threadIdx.x;
  if (i >= BATCH) return;
  float lterm = fmaxf(0.6f - 0.5f * (*l_all), 0.0f);
  float z = (tot_in[i] + lterm) * 0.01f;
  out[i] = fmaxf(1.0f - xla_tanh(z), 0.0f);
}

extern "C" void kernel_launch(void* const* d_in, const int* in_sizes, int n_in,
                              void* d_out, int out_size, void* d_ws, size_t ws_size,
                              hipStream_t stream) {
  const float* x     = (const float*)d_in[0];
  const float* x_bw  = (const float*)d_in[1];
  const float* alpha = (const float*)d_in[2];
  const float* beta  = (const float*)d_in[3];
  const float* Omega = (const float*)d_in[4];
  const int* sector_id = (const int*)d_in[5];
  const int* mq_id     = (const int*)d_in[6];
  float* out = (float*)d_out;

  char* ws = (char*)d_ws;
  u16*   wsA    = (u16*)ws;                          // 544 KB fragment stream
  float* thr    = (float*)(ws + 544 * 1024);         // 2 KB nnz thresholds
  float* smalls = (float*)(ws + 544 * 1024 + 2048);  // [0]=sum(x_bw), [1]=l_all
  float* tot    = (float*)(ws + 544 * 1024 + 4096);  // 512 KB per-row tot

  disc_prep<<<1088, 256, 0, stream>>>(Omega, alpha, beta, x_bw, sector_id, mq_id,
                                      wsA, thr, smalls);
  disc_main<<<BATCH / BM, 512, 0, stream>>>(x, x_bw, wsA, thr, smalls,
                                            tot, smalls + 1);
  disc_final<<<BATCH / 256, 256, 0, stream>>>(tot, smalls + 1, out);
}